// Round 7
// baseline (6872.944 us; speedup 1.0000x reference)
//
#include <hip/hip_runtime.h>
#include <math.h>

#define B_    32
#define S_    512
#define EMB_  512
#define HID_  1024
#define LAB_  64
#define M_    (B_ * S_)

// ---------------------------------------------------------------------------
// Fence-free h exchange: one 64-bit word per (batch,neuron) = (tag<<32)|bits.
// Relaxed agent atomics only — no fences, no per-step cache maintenance.
// Tags: layer0 1..512, layer1 513..1024; 0 and 0xAAAAAAAA (poison) never
// match. Depth-2 slots: writing tag t implies all WGs published t-1, which
// implies all WGs finished reading slot t-2 (the slot being overwritten).
// ---------------------------------------------------------------------------
#define EX_SLOT (B_ * HID_)   // u64 words per slot; 2 slots = 512 KB in d_out

__device__ __forceinline__ unsigned long long aload64(const unsigned long long* p) {
    return __hip_atomic_load((unsigned long long*)p, __ATOMIC_RELAXED,
                             __HIP_MEMORY_SCOPE_AGENT);
}
__device__ __forceinline__ void astore64(unsigned long long* p, unsigned long long v) {
    __hip_atomic_store(p, v, __ATOMIC_RELAXED, __HIP_MEMORY_SCOPE_AGENT);
}

// ---------------------------------------------------------------------------
// fp32 tiled GEMM, R7 retile: BM=128, BN=64, BK=16, 256 threads, 8x4/thread.
// Optional row-gather on A. M%128==0, N%64==0, K%16==0 (all uses satisfy).
// Bank audit: As reads broadcast 4 banks (stride 17), Ws reads 16 banks.
// ---------------------------------------------------------------------------
__global__ __launch_bounds__(256) void gemm_bias(
    const float* __restrict__ A, const int* __restrict__ tokens,
    const float* __restrict__ W, const float* __restrict__ bias,
    const float* __restrict__ bias2, float* __restrict__ C,
    int M, int K, int N)
{
    __shared__ float As[128][17];
    __shared__ float Ws[64][17];

    const int tid = threadIdx.x;
    const int tx  = tid & 15;             // n-group: 4 cols
    const int ty  = tid >> 4;             // 0..15: 8 rows
    const int n0  = blockIdx.x * 64;
    const int m0  = blockIdx.y * 128;

    const int lr  = tid >> 2;             // 0..63
    const int lk  = (tid & 3) << 2;

    const int ar0 = tokens ? tokens[m0 + lr]      : (m0 + lr);
    const int ar1 = tokens ? tokens[m0 + 64 + lr] : (m0 + 64 + lr);
    const float* __restrict__ arow0 = A + (size_t)ar0 * K;
    const float* __restrict__ arow1 = A + (size_t)ar1 * K;
    const float* __restrict__ wrow  = W + (size_t)(n0 + lr) * K;

    float bs[4];
#pragma unroll
    for (int j = 0; j < 4; ++j) {
        int n = n0 + tx * 4 + j;
        bs[j] = bias[n] + (bias2 ? bias2[n] : 0.0f);
    }

    float acc[8][4] = {};

    for (int k0 = 0; k0 < K; k0 += 16) {
        const float4 a0 = *(const float4*)(arow0 + k0 + lk);
        const float4 a1 = *(const float4*)(arow1 + k0 + lk);
        const float4 wv = *(const float4*)(wrow  + k0 + lk);
        __syncthreads();   // prev iteration's readers done
        As[lr][lk + 0] = a0.x; As[lr][lk + 1] = a0.y;
        As[lr][lk + 2] = a0.z; As[lr][lk + 3] = a0.w;
        As[64 + lr][lk + 0] = a1.x; As[64 + lr][lk + 1] = a1.y;
        As[64 + lr][lk + 2] = a1.z; As[64 + lr][lk + 3] = a1.w;
        Ws[lr][lk + 0] = wv.x; Ws[lr][lk + 1] = wv.y;
        Ws[lr][lk + 2] = wv.z; Ws[lr][lk + 3] = wv.w;
        __syncthreads();

#pragma unroll
        for (int kk = 0; kk < 16; ++kk) {
            float b[4], a[8];
#pragma unroll
            for (int j = 0; j < 4; ++j) b[j] = Ws[tx * 4 + j][kk];
#pragma unroll
            for (int i = 0; i < 8; ++i) a[i] = As[ty * 8 + i][kk];
#pragma unroll
            for (int i = 0; i < 8; ++i)
#pragma unroll
                for (int j = 0; j < 4; ++j)
                    acc[i][j] += a[i] * b[j];
        }
    }

#pragma unroll
    for (int i = 0; i < 8; ++i) {
        const int m = m0 + ty * 8 + i;
        float4 v;
        v.x = acc[i][0] + bs[0];
        v.y = acc[i][1] + bs[1];
        v.z = acc[i][2] + bs[2];
        v.w = acc[i][3] + bs[3];
        *(float4*)(C + (size_t)m * N + n0 + tx * 4) = v;
    }
}

// ---------------------------------------------------------------------------
// Weight-stationary persistent scan, R7. Same dataflow as R6; serial chain
// cuts: merged 8-word poll, xp prefetch at step top, intra-wave shfl_xor
// k-reduction (red LDS phase + 3rd barrier eliminated), publish-first.
// 256 WGs x 512 threads, 1 WG/CU (96 KB dyn LDS). Thread (j8=tid>>6, kg=
// tid&63): wave j8 owns neurons s*32+j8*4..+3; k-split 64 is intra-wave.
// ---------------------------------------------------------------------------
__global__ __launch_bounds__(512, 2) void rnn_scan_tag(
    const float* __restrict__ Whh,          // [H][H] row-major
    float* __restrict__ x,                  // [B,S,H]  xp in, h out (in place)
    unsigned long long* __restrict__ ex,    // [2][B_][HID_] tagged exchange
    unsigned tag0)                          // 1 (layer0) / 513 (layer1)
{
    extern __shared__ float smem[];
    float4* hl4 = (float4*)smem;            // 1024 float4 = 16 KB

    const int wg  = blockIdx.x;
    const int bg  = wg & 7;
    const int s   = wg >> 3;
    const int tid = threadIdx.x;     // 0..511
    const int j8  = tid >> 6;        // 0..7 (the wave)
    const int kg  = tid & 63;        // lane; k = kg + 64q
    const int b0  = bg * 4;

    // weights: 4 neurons x 16 strided k = 64 VGPRs (lane-coalesced loads)
    float wreg[4][16];
    {
        const float* wb = Whh + (size_t)(s * 32 + j8 * 4) * HID_ + kg;
#pragma unroll
        for (int i = 0; i < 4; ++i)
#pragma unroll
            for (int q = 0; q < 16; ++q)
                wreg[i][q] = wb[(size_t)i * HID_ + q * 64];
    }

    const int oi = kg >> 2, ob = kg & 3;           // this lane's output
    const int ok = s * 32 + j8 * 4 + oi;           // neuron index

    for (int t = 0; t < S_; ++t) {
        // ---- xp prefetch: independent of h, overlaps the poll ----
        float xpv = 0.f;
        float* px = nullptr;
        if (kg < 16) {
            px  = x + ((size_t)(b0 + ob) * S_ + t) * HID_ + ok;
            xpv = *px;                              // use is after reduce
        }

        __syncthreads();   // prev iter's hl4 readers done

        // ---- stage h_{t-1}: merged 8-word tagged poll (relaxed) ----
        if (t > 0) {
            const unsigned wtag = tag0 + (unsigned)(t - 1);
            const unsigned long long* exs = ex + (size_t)((t - 1) & 1) * EX_SLOT;
            unsigned long long w[2][4];
            unsigned pend = 0xffu;
            do {
#pragma unroll
                for (int c = 0; c < 2; ++c)
#pragma unroll
                    for (int j = 0; j < 4; ++j) {
                        const unsigned bit = 1u << (c * 4 + j);
                        if (pend & bit) {
                            unsigned long long u = aload64(
                                exs + (size_t)(b0 + j) * HID_ + tid + 512 * c);
                            if ((unsigned)(u >> 32) == wtag) {
                                w[c][j] = u;
                                pend &= ~bit;
                            }
                        }
                    }
            } while (pend);
#pragma unroll
            for (int c = 0; c < 2; ++c) {
                float4 v;
                v.x = __uint_as_float((unsigned)w[c][0]);
                v.y = __uint_as_float((unsigned)w[c][1]);
                v.z = __uint_as_float((unsigned)w[c][2]);
                v.w = __uint_as_float((unsigned)w[c][3]);
                hl4[tid + 512 * c] = v;             // contiguous b128: free
            }
        } else {
#pragma unroll
            for (int c = 0; c < 2; ++c)
                hl4[tid + 512 * c] = make_float4(0.f, 0.f, 0.f, 0.f);
        }
        __syncthreads();

        // ---- partials: 4 neurons x 4 batches over 16 strided k ----
        float acc[4][4] = {};
#pragma unroll
        for (int q = 0; q < 16; ++q) {
            const float4 hv = hl4[kg + 64 * q];     // lane-contig: free
#pragma unroll
            for (int i = 0; i < 4; ++i) {
                const float w = wreg[i][q];
                acc[i][0] += w * hv.x;
                acc[i][1] += w * hv.y;
                acc[i][2] += w * hv.z;
                acc[i][3] += w * hv.w;
            }
        }

        // ---- intra-wave 64-lane butterfly reduction (k-split is the lane) ----
#pragma unroll
        for (int m = 1; m < 64; m <<= 1)
#pragma unroll
            for (int i = 0; i < 4; ++i)
#pragma unroll
                for (int b = 0; b < 4; ++b)
                    acc[i][b] += __shfl_xor(acc[i][b], m, 64);

        // ---- lanes 0..15 publish their (neuron oi, batch ob) ----
        if (kg < 16) {
            float sum = acc[0][0];                  // static-index select chain
#pragma unroll
            for (int i = 0; i < 4; ++i)
#pragma unroll
                for (int b = 0; b < 4; ++b)
                    if (kg == i * 4 + b) sum = acc[i][b];
            const float hv = tanhf(xpv + sum);
            const unsigned long long u =
                ((unsigned long long)(tag0 + (unsigned)t) << 32) |
                (unsigned long long)__float_as_uint(hv);
            astore64(ex + (size_t)(t & 1) * EX_SLOT
                        + (size_t)(b0 + ob) * HID_ + ok, u);   // publish first
            *px = hv;                               // for the next-layer GEMM
        }
        // no trailing barrier: next iter's top barrier covers hl4
    }
}

__global__ __launch_bounds__(256) void copy4(
    const float4* __restrict__ src, float4* __restrict__ dst, int n4)
{
    const int i = blockIdx.x * 256 + threadIdx.x;
    if (i < n4) dst[i] = src[i];
}

extern "C" void kernel_launch(void* const* d_in, const int* in_sizes, int n_in,
                              void* d_out, int out_size, void* d_ws, size_t ws_size,
                              hipStream_t stream)
{
    const int*   tokens = (const int*)  d_in[0];
    const float* emb    = (const float*)d_in[1];
    const float* W_ih0  = (const float*)d_in[2];
    const float* W_hh0  = (const float*)d_in[3];
    const float* b_ih0  = (const float*)d_in[4];
    const float* b_hh0  = (const float*)d_in[5];
    const float* W_ih1  = (const float*)d_in[6];
    const float* W_hh1  = (const float*)d_in[7];
    const float* b_ih1  = (const float*)d_in[8];
    const float* b_hh1  = (const float*)d_in[9];
    const float* W_out  = (const float*)d_in[10];
    const float* b_out  = (const float*)d_in[11];
    float* out = (float*)d_out;

    const size_t BUF = (size_t)B_ * S_ * HID_;   // 64 MiB
    float* buf  = (float*)d_ws;
    float* buf1 = buf + BUF;                     // only if ws_size permits
    float* tmp  = (float*)d_out;                 // chunk bounce (fallback)
    unsigned long long* ex = (unsigned long long*)d_out;  // 512 KB exchange

    const int two_buf = (ws_size >= 2 * BUF * sizeof(float));  // constant/call

    // 96 KB dynamic LDS -> exactly 1 WG/CU (256 WGs co-resident on 256 CUs)
    const size_t scan_lds = 98304;
    hipFuncSetAttribute((const void*)rnn_scan_tag,
                        hipFuncAttributeMaxDynamicSharedMemorySize, (int)scan_lds);

    // 1) xp0 = gather(emb,tokens) @ W_ih0^T + b_ih0 + b_hh0  -> buf
    gemm_bias<<<dim3(HID_ / 64, M_ / 128), 256, 0, stream>>>(
        emb, tokens, W_ih0, b_ih0, b_hh0, buf, M_, EMB_, HID_);

    // 2) layer-0 scan (in place on buf; tags 1..512)
    rnn_scan_tag<<<256, 512, scan_lds, stream>>>(W_hh0, buf, ex, 1u);

    float* l1buf;
    if (two_buf) {
        // 3a) full-grid xp1 GEMM into buf1
        gemm_bias<<<dim3(HID_ / 64, M_ / 128), 256, 0, stream>>>(
            buf, nullptr, W_ih1, b_ih1, b_hh1, buf1, M_, HID_, HID_);
        l1buf = buf1;
    } else {
        // 3b) fallback: chunk through d_out (ex region dead until next scan)
        for (int c = 0; c < 16; ++c) {
            const float* Ac = buf + (size_t)c * 1024 * HID_;
            gemm_bias<<<dim3(HID_ / 64, 1024 / 128), 256, 0, stream>>>(
                Ac, nullptr, W_ih1, b_ih1, b_hh1, tmp, 1024, HID_, HID_);
            copy4<<<1024, 256, 0, stream>>>(
                (const float4*)tmp, (float4*)(buf + (size_t)c * 1024 * HID_),
                1024 * HID_ / 4);
        }
        l1buf = buf;
    }

    // 4) layer-1 scan (tags 513..1024; stale/garbage high words never match)
    rnn_scan_tag<<<256, 512, scan_lds, stream>>>(W_hh1, l1buf, ex, 513u);

    // 5) out = h1 @ W_out^T + b_out (fully rewrites d_out incl. ex region)
    gemm_bias<<<dim3(LAB_ / 64, M_ / 128), 256, 0, stream>>>(
        l1buf, nullptr, W_out, b_out, nullptr, out, M_, HID_, LAB_);
}

// Round 8
// 5118.633 us; speedup vs baseline: 1.3427x; 1.3427x over previous
//
#include <hip/hip_runtime.h>
#include <math.h>

#define B_    32
#define S_    512
#define EMB_  512
#define HID_  1024
#define LAB_  64
#define M_    (B_ * S_)

// ---------------------------------------------------------------------------
// Fence-free h exchange: one 64-bit word per (batch,neuron) = (tag<<32)|bits.
// Relaxed agent atomics only — no fences, no per-step cache maintenance.
// Tags: layer0 1..512, layer1 513..1024; 0 and 0xAAAAAAAA (poison) never
// match. Depth-2 slots: writing tag t implies all WGs published t-1, which
// implies all WGs finished reading slot t-2 (the slot being overwritten).
// ---------------------------------------------------------------------------
#define EX_SLOT (B_ * HID_)   // u64 words per slot; 2 slots = 512 KB in d_out

__device__ __forceinline__ unsigned long long aload64(const unsigned long long* p) {
    return __hip_atomic_load((unsigned long long*)p, __ATOMIC_RELAXED,
                             __HIP_MEMORY_SCOPE_AGENT);
}
__device__ __forceinline__ void astore64(unsigned long long* p, unsigned long long v) {
    __hip_atomic_store(p, v, __ATOMIC_RELAXED, __HIP_MEMORY_SCOPE_AGENT);
}

// ---------------------------------------------------------------------------
// fp32 tiled GEMM, BM=128, BN=64, BK=16, 256 threads, 8x4/thread (R7 tile —
// measured GEMM total ~0.79 ms). Optional row-gather on A.
// ---------------------------------------------------------------------------
__global__ __launch_bounds__(256) void gemm_bias(
    const float* __restrict__ A, const int* __restrict__ tokens,
    const float* __restrict__ W, const float* __restrict__ bias,
    const float* __restrict__ bias2, float* __restrict__ C,
    int M, int K, int N)
{
    __shared__ float As[128][17];
    __shared__ float Ws[64][17];

    const int tid = threadIdx.x;
    const int tx  = tid & 15;
    const int ty  = tid >> 4;
    const int n0  = blockIdx.x * 64;
    const int m0  = blockIdx.y * 128;

    const int lr  = tid >> 2;
    const int lk  = (tid & 3) << 2;

    const int ar0 = tokens ? tokens[m0 + lr]      : (m0 + lr);
    const int ar1 = tokens ? tokens[m0 + 64 + lr] : (m0 + 64 + lr);
    const float* __restrict__ arow0 = A + (size_t)ar0 * K;
    const float* __restrict__ arow1 = A + (size_t)ar1 * K;
    const float* __restrict__ wrow  = W + (size_t)(n0 + lr) * K;

    float bs[4];
#pragma unroll
    for (int j = 0; j < 4; ++j) {
        int n = n0 + tx * 4 + j;
        bs[j] = bias[n] + (bias2 ? bias2[n] : 0.0f);
    }

    float acc[8][4] = {};

    for (int k0 = 0; k0 < K; k0 += 16) {
        const float4 a0 = *(const float4*)(arow0 + k0 + lk);
        const float4 a1 = *(const float4*)(arow1 + k0 + lk);
        const float4 wv = *(const float4*)(wrow  + k0 + lk);
        __syncthreads();
        As[lr][lk + 0] = a0.x; As[lr][lk + 1] = a0.y;
        As[lr][lk + 2] = a0.z; As[lr][lk + 3] = a0.w;
        As[64 + lr][lk + 0] = a1.x; As[64 + lr][lk + 1] = a1.y;
        As[64 + lr][lk + 2] = a1.z; As[64 + lr][lk + 3] = a1.w;
        Ws[lr][lk + 0] = wv.x; Ws[lr][lk + 1] = wv.y;
        Ws[lr][lk + 2] = wv.z; Ws[lr][lk + 3] = wv.w;
        __syncthreads();

#pragma unroll
        for (int kk = 0; kk < 16; ++kk) {
            float b[4], a[8];
#pragma unroll
            for (int j = 0; j < 4; ++j) b[j] = Ws[tx * 4 + j][kk];
#pragma unroll
            for (int i = 0; i < 8; ++i) a[i] = As[ty * 8 + i][kk];
#pragma unroll
            for (int i = 0; i < 8; ++i)
#pragma unroll
                for (int j = 0; j < 4; ++j)
                    acc[i][j] += a[i] * b[j];
        }
    }

#pragma unroll
    for (int i = 0; i < 8; ++i) {
        const int m = m0 + ty * 8 + i;
        float4 v;
        v.x = acc[i][0] + bs[0];
        v.y = acc[i][1] + bs[1];
        v.z = acc[i][2] + bs[2];
        v.w = acc[i][3] + bs[3];
        *(float4*)(C + (size_t)m * N + n0 + tx * 4) = v;
    }
}

// ---------------------------------------------------------------------------
// Weight-stationary persistent scan, R8. R7 minus the 96-shfl butterfly
// (the measured regression): replaced by the 17-shfl halving tree.
//   stage m∈{1,2,4,8}: v[j] = (bit ? a1 : a0) + shfl_xor(bit ? a0 : a1, m)
//   -> acc count 16->8->4->2->1; lane bits 0-3 select the acc family, so
//   after masks 16,32 lane p holds out(p&15). Publish = lanes 0..15 direct.
// Kept from R7: merged 8-word poll, xp prefetch at top, publish-first.
// 256 WGs x 512 threads, 1 WG/CU (96 KB dyn LDS), XCD-affine batch groups.
// ---------------------------------------------------------------------------
__global__ __launch_bounds__(512, 2) void rnn_scan_tag(
    const float* __restrict__ Whh,          // [H][H] row-major
    float* __restrict__ x,                  // [B,S,H]  xp in, h out (in place)
    unsigned long long* __restrict__ ex,    // [2][B_][HID_] tagged exchange
    unsigned tag0)                          // 1 (layer0) / 513 (layer1)
{
    extern __shared__ float smem[];
    float4* hl4 = (float4*)smem;            // 1024 float4 = 16 KB

    const int wg  = blockIdx.x;
    const int bg  = wg & 7;
    const int s   = wg >> 3;
    const int tid = threadIdx.x;     // 0..511
    const int j8  = tid >> 6;        // 0..7 (the wave)
    const int kg  = tid & 63;        // lane; k = kg + 64q
    const int b0  = bg * 4;

    // weights: 4 neurons x 16 strided k = 64 VGPRs (lane-coalesced loads)
    float wreg[4][16];
    {
        const float* wb = Whh + (size_t)(s * 32 + j8 * 4) * HID_ + kg;
#pragma unroll
        for (int i = 0; i < 4; ++i)
#pragma unroll
            for (int q = 0; q < 16; ++q)
                wreg[i][q] = wb[(size_t)i * HID_ + q * 64];
    }

    const int oi = kg >> 2, ob = kg & 3;           // lane's output (kg<16)
    const int ok = s * 32 + j8 * 4 + oi;           // neuron index

    for (int t = 0; t < S_; ++t) {
        // ---- xp prefetch: independent of h, overlaps the poll ----
        float xpv = 0.f;
        float* px = nullptr;
        if (kg < 16) {
            px  = x + ((size_t)(b0 + ob) * S_ + t) * HID_ + ok;
            xpv = *px;
        }

        __syncthreads();   // prev iter's hl4 readers done

        // ---- stage h_{t-1}: merged 8-word tagged poll (relaxed) ----
        if (t > 0) {
            const unsigned wtag = tag0 + (unsigned)(t - 1);
            const unsigned long long* exs = ex + (size_t)((t - 1) & 1) * EX_SLOT;
            unsigned long long w[2][4];
            unsigned pend = 0xffu;
            do {
#pragma unroll
                for (int c = 0; c < 2; ++c)
#pragma unroll
                    for (int j = 0; j < 4; ++j) {
                        const unsigned bit = 1u << (c * 4 + j);
                        if (pend & bit) {
                            unsigned long long u = aload64(
                                exs + (size_t)(b0 + j) * HID_ + tid + 512 * c);
                            if ((unsigned)(u >> 32) == wtag) {
                                w[c][j] = u;
                                pend &= ~bit;
                            }
                        }
                    }
            } while (pend);
#pragma unroll
            for (int c = 0; c < 2; ++c) {
                float4 v;
                v.x = __uint_as_float((unsigned)w[c][0]);
                v.y = __uint_as_float((unsigned)w[c][1]);
                v.z = __uint_as_float((unsigned)w[c][2]);
                v.w = __uint_as_float((unsigned)w[c][3]);
                hl4[tid + 512 * c] = v;             // contiguous b128: free
            }
        } else {
#pragma unroll
            for (int c = 0; c < 2; ++c)
                hl4[tid + 512 * c] = make_float4(0.f, 0.f, 0.f, 0.f);
        }
        __syncthreads();

        // ---- partials: v[a], a = i*4+b, over 16 strided k ----
        float v[16] = {};
#pragma unroll
        for (int q = 0; q < 16; ++q) {
            const float4 hv = hl4[kg + 64 * q];     // lane-contig: free
#pragma unroll
            for (int i = 0; i < 4; ++i) {
                const float w = wreg[i][q];
                v[i * 4 + 0] += w * hv.x;
                v[i * 4 + 1] += w * hv.y;
                v[i * 4 + 2] += w * hv.z;
                v[i * 4 + 3] += w * hv.w;
            }
        }

        // ---- halving-tree reduction: 15 shfls fold 16 accs -> 1 ----
#pragma unroll
        for (int st = 0; st < 4; ++st) {
            const int m  = 1 << st;
            const int nh = 8 >> st;                 // pairs this stage
            const bool hi = (kg & m) != 0;
#pragma unroll
            for (int j = 0; j < 8; ++j) {
                if (j < nh) {
                    const float a0 = v[2 * j], a1 = v[2 * j + 1];
                    const float got = __shfl_xor(hi ? a0 : a1, m, 64);
                    v[j] = (hi ? a1 : a0) + got;
                }
            }
        }
        v[0] += __shfl_xor(v[0], 16, 64);
        v[0] += __shfl_xor(v[0], 32, 64);
        // lane p now holds out(p & 15)

        // ---- lanes 0..15 publish their (neuron oi, batch ob) ----
        if (kg < 16) {
            const float hv = tanhf(xpv + v[0]);
            const unsigned long long u =
                ((unsigned long long)(tag0 + (unsigned)t) << 32) |
                (unsigned long long)__float_as_uint(hv);
            astore64(ex + (size_t)(t & 1) * EX_SLOT
                        + (size_t)(b0 + ob) * HID_ + ok, u);   // publish first
            *px = hv;                               // for the next-layer GEMM
        }
        // no trailing barrier: next iter's top barrier covers hl4
    }
}

__global__ __launch_bounds__(256) void copy4(
    const float4* __restrict__ src, float4* __restrict__ dst, int n4)
{
    const int i = blockIdx.x * 256 + threadIdx.x;
    if (i < n4) dst[i] = src[i];
}

extern "C" void kernel_launch(void* const* d_in, const int* in_sizes, int n_in,
                              void* d_out, int out_size, void* d_ws, size_t ws_size,
                              hipStream_t stream)
{
    const int*   tokens = (const int*)  d_in[0];
    const float* emb    = (const float*)d_in[1];
    const float* W_ih0  = (const float*)d_in[2];
    const float* W_hh0  = (const float*)d_in[3];
    const float* b_ih0  = (const float*)d_in[4];
    const float* b_hh0  = (const float*)d_in[5];
    const float* W_ih1  = (const float*)d_in[6];
    const float* W_hh1  = (const float*)d_in[7];
    const float* b_ih1  = (const float*)d_in[8];
    const float* b_hh1  = (const float*)d_in[9];
    const float* W_out  = (const float*)d_in[10];
    const float* b_out  = (const float*)d_in[11];
    float* out = (float*)d_out;

    const size_t BUF = (size_t)B_ * S_ * HID_;   // 64 MiB
    float* buf  = (float*)d_ws;
    float* buf1 = buf + BUF;                     // only if ws_size permits
    float* tmp  = (float*)d_out;                 // chunk bounce (fallback)
    unsigned long long* ex = (unsigned long long*)d_out;  // 512 KB exchange

    const int two_buf = (ws_size >= 2 * BUF * sizeof(float));  // constant/call

    // 96 KB dynamic LDS -> exactly 1 WG/CU (256 WGs co-resident on 256 CUs)
    const size_t scan_lds = 98304;
    hipFuncSetAttribute((const void*)rnn_scan_tag,
                        hipFuncAttributeMaxDynamicSharedMemorySize, (int)scan_lds);

    // 1) xp0 = gather(emb,tokens) @ W_ih0^T + b_ih0 + b_hh0  -> buf
    gemm_bias<<<dim3(HID_ / 64, M_ / 128), 256, 0, stream>>>(
        emb, tokens, W_ih0, b_ih0, b_hh0, buf, M_, EMB_, HID_);

    // 2) layer-0 scan (in place on buf; tags 1..512)
    rnn_scan_tag<<<256, 512, scan_lds, stream>>>(W_hh0, buf, ex, 1u);

    float* l1buf;
    if (two_buf) {
        // 3a) full-grid xp1 GEMM into buf1
        gemm_bias<<<dim3(HID_ / 64, M_ / 128), 256, 0, stream>>>(
            buf, nullptr, W_ih1, b_ih1, b_hh1, buf1, M_, HID_, HID_);
        l1buf = buf1;
    } else {
        // 3b) fallback: chunk through d_out (ex region dead until next scan)
        for (int c = 0; c < 16; ++c) {
            const float* Ac = buf + (size_t)c * 1024 * HID_;
            gemm_bias<<<dim3(HID_ / 64, 1024 / 128), 256, 0, stream>>>(
                Ac, nullptr, W_ih1, b_ih1, b_hh1, tmp, 1024, HID_, HID_);
            copy4<<<1024, 256, 0, stream>>>(
                (const float4*)tmp, (float4*)(buf + (size_t)c * 1024 * HID_),
                1024 * HID_ / 4);
        }
        l1buf = buf;
    }

    // 4) layer-1 scan (tags 513..1024; stale/garbage high words never match)
    rnn_scan_tag<<<256, 512, scan_lds, stream>>>(W_hh1, l1buf, ex, 513u);

    // 5) out = h1 @ W_out^T + b_out (fully rewrites d_out incl. ex region)
    gemm_bias<<<dim3(LAB_ / 64, M_ / 128), 256, 0, stream>>>(
        l1buf, nullptr, W_out, b_out, nullptr, out, M_, HID_, LAB_);
}

// Round 9
// 4226.823 us; speedup vs baseline: 1.6260x; 1.2110x over previous
//
#include <hip/hip_runtime.h>
#include <math.h>

#define B_    32
#define S_    512
#define EMB_  512
#define HID_  1024
#define LAB_  64
#define M_    (B_ * S_)

// ---------------------------------------------------------------------------
// Fence-free h exchange: one 64-bit word per (batch,neuron) = (tag<<32)|bits.
// Relaxed agent atomics only. Tags: layer0 1..512, layer1 513..1024; 0 and
// 0xAAAAAAAA never match. Depth-2 slots: writing tag t implies all WGs of the
// group published t-1, which implies all finished reading slot t-2.
// ---------------------------------------------------------------------------
#define EX_SLOT (B_ * HID_)   // u64 words per slot; 2 slots = 512 KB in d_out

__device__ __forceinline__ unsigned long long aload64(const unsigned long long* p) {
    return __hip_atomic_load((unsigned long long*)p, __ATOMIC_RELAXED,
                             __HIP_MEMORY_SCOPE_AGENT);
}
__device__ __forceinline__ void astore64(unsigned long long* p, unsigned long long v) {
    __hip_atomic_store(p, v, __ATOMIC_RELAXED, __HIP_MEMORY_SCOPE_AGENT);
}

// ---------------------------------------------------------------------------
// fp32 tiled GEMM, BM=128, BN=64, BK=16, 256 threads, 8x4/thread (measured
// ~0.79 ms total across the three projections). Optional row-gather on A.
// ---------------------------------------------------------------------------
__global__ __launch_bounds__(256) void gemm_bias(
    const float* __restrict__ A, const int* __restrict__ tokens,
    const float* __restrict__ W, const float* __restrict__ bias,
    const float* __restrict__ bias2, float* __restrict__ C,
    int M, int K, int N)
{
    __shared__ float As[128][17];
    __shared__ float Ws[64][17];

    const int tid = threadIdx.x;
    const int tx  = tid & 15;
    const int ty  = tid >> 4;
    const int n0  = blockIdx.x * 64;
    const int m0  = blockIdx.y * 128;

    const int lr  = tid >> 2;
    const int lk  = (tid & 3) << 2;

    const int ar0 = tokens ? tokens[m0 + lr]      : (m0 + lr);
    const int ar1 = tokens ? tokens[m0 + 64 + lr] : (m0 + 64 + lr);
    const float* __restrict__ arow0 = A + (size_t)ar0 * K;
    const float* __restrict__ arow1 = A + (size_t)ar1 * K;
    const float* __restrict__ wrow  = W + (size_t)(n0 + lr) * K;

    float bs[4];
#pragma unroll
    for (int j = 0; j < 4; ++j) {
        int n = n0 + tx * 4 + j;
        bs[j] = bias[n] + (bias2 ? bias2[n] : 0.0f);
    }

    float acc[8][4] = {};

    for (int k0 = 0; k0 < K; k0 += 16) {
        const float4 a0 = *(const float4*)(arow0 + k0 + lk);
        const float4 a1 = *(const float4*)(arow1 + k0 + lk);
        const float4 wv = *(const float4*)(wrow  + k0 + lk);
        __syncthreads();
        As[lr][lk + 0] = a0.x; As[lr][lk + 1] = a0.y;
        As[lr][lk + 2] = a0.z; As[lr][lk + 3] = a0.w;
        As[64 + lr][lk + 0] = a1.x; As[64 + lr][lk + 1] = a1.y;
        As[64 + lr][lk + 2] = a1.z; As[64 + lr][lk + 3] = a1.w;
        Ws[lr][lk + 0] = wv.x; Ws[lr][lk + 1] = wv.y;
        Ws[lr][lk + 2] = wv.z; Ws[lr][lk + 3] = wv.w;
        __syncthreads();

#pragma unroll
        for (int kk = 0; kk < 16; ++kk) {
            float b[4], a[8];
#pragma unroll
            for (int j = 0; j < 4; ++j) b[j] = Ws[tx * 4 + j][kk];
#pragma unroll
            for (int i = 0; i < 8; ++i) a[i] = As[ty * 8 + i][kk];
#pragma unroll
            for (int i = 0; i < 8; ++i)
#pragma unroll
                for (int j = 0; j < 4; ++j)
                    acc[i][j] += a[i] * b[j];
        }
    }

#pragma unroll
    for (int i = 0; i < 8; ++i) {
        const int m = m0 + ty * 8 + i;
        float4 v;
        v.x = acc[i][0] + bs[0];
        v.y = acc[i][1] + bs[1];
        v.z = acc[i][2] + bs[2];
        v.w = acc[i][3] + bs[3];
        *(float4*)(C + (size_t)m * N + n0 + tx * 4) = v;
    }
}

// ---------------------------------------------------------------------------
// Weight-stationary persistent scan, R9: regrouped to cut poll fan-in.
// 256 WGs x 512 threads, 1 WG/CU. Group = wg&15 (16 groups x 2 batches,
// XCD-affine: wg%8 constant within a group). Slice s = wg>>4: 64 neurons.
// Per WG poll traffic: 2048 words/step (half of R8). Weights in registers:
// 8 neurons x 16 strided k = 128 VGPRs (launch_bounds(512,2) -> 256 cap).
// LDS h: float2[1024] DOUBLE-BUFFERED -> ONE barrier per step. Safety: a
// thread's reads of buf[(t-1)&1] precede (program order) its staging of
// buf[t&1], which precedes barrier_t; any thread writes buf[(t+1)&1] =
// buf[(t-1)&1] only after passing barrier_t. 16-acc halving-tree reduction
// (a = i*2+b): after masks 1,2,4,8 + 16,32, lane p holds out(p&15).
// ---------------------------------------------------------------------------
__global__ __launch_bounds__(512, 2) void rnn_scan_tag(
    const float* __restrict__ Whh,          // [H][H] row-major
    float* __restrict__ x,                  // [B,S,H]  xp in, h out (in place)
    unsigned long long* __restrict__ ex,    // [2][B_][HID_] tagged exchange
    unsigned tag0)                          // 1 (layer0) / 513 (layer1)
{
    extern __shared__ float smem[];
    float2* hb2 = (float2*)smem;            // [2][1024] float2 = 16 KB

    const int wg  = blockIdx.x;
    const int bg  = wg & 15;         // batch group (2 batches)
    const int s   = wg >> 4;         // slice 0..15 (64 neurons)
    const int tid = threadIdx.x;     // 0..511
    const int j8  = tid >> 6;        // wave 0..7 -> neurons s*64 + j8*8 ..+7
    const int kg  = tid & 63;        // lane; k = kg + 64q
    const int b0  = bg * 2;

    // weights: 8 neurons x 16 strided k = 128 VGPRs (lane-coalesced loads)
    float wreg[8][16];
    {
        const float* wb = Whh + (size_t)(s * 64 + j8 * 8) * HID_ + kg;
#pragma unroll
        for (int i = 0; i < 8; ++i)
#pragma unroll
            for (int q = 0; q < 16; ++q)
                wreg[i][q] = wb[(size_t)i * HID_ + q * 64];
    }

    const int oi = (kg >> 1) & 7, ob = kg & 1;     // lane's output (kg<16)
    const int ok = s * 64 + j8 * 8 + oi;           // neuron index

    for (int t = 0; t < S_; ++t) {
        float2* cur = hb2 + (size_t)(t & 1) * HID_;

        // ---- xp prefetch: independent of h, overlaps the poll ----
        float xpv = 0.f;
        float* px = nullptr;
        if (kg < 16) {
            px  = x + ((size_t)(b0 + ob) * S_ + t) * HID_ + ok;
            xpv = *px;
        }

        // ---- stage h_{t-1}: merged 4-word tagged poll (relaxed) ----
        if (t > 0) {
            const unsigned wtag = tag0 + (unsigned)(t - 1);
            const unsigned long long* exs = ex + (size_t)((t - 1) & 1) * EX_SLOT;
            unsigned long long w[2][2];      // [m-chunk][batch]
            unsigned pend = 0xfu;
            do {
#pragma unroll
                for (int c = 0; c < 2; ++c)
#pragma unroll
                    for (int j = 0; j < 2; ++j) {
                        const unsigned bit = 1u << (c * 2 + j);
                        if (pend & bit) {
                            unsigned long long u = aload64(
                                exs + (size_t)(b0 + j) * HID_ + tid + 512 * c);
                            if ((unsigned)(u >> 32) == wtag) {
                                w[c][j] = u;
                                pend &= ~bit;
                            }
                        }
                    }
            } while (pend);
#pragma unroll
            for (int c = 0; c < 2; ++c) {
                float2 v;
                v.x = __uint_as_float((unsigned)w[c][0]);
                v.y = __uint_as_float((unsigned)w[c][1]);
                cur[tid + 512 * c] = v;       // contiguous b64: conflict-free
            }
        } else {
#pragma unroll
            for (int c = 0; c < 2; ++c)
                cur[tid + 512 * c] = make_float2(0.f, 0.f);
        }
        __syncthreads();   // the ONE barrier: staging done -> compute reads

        // ---- partials: v[a], a = i*2+b, over 16 strided k ----
        float v[16] = {};
#pragma unroll
        for (int q = 0; q < 16; ++q) {
            const float2 hv = cur[kg + 64 * q];    // lane-contig b64: free
#pragma unroll
            for (int i = 0; i < 8; ++i) {
                const float w = wreg[i][q];
                v[i * 2 + 0] += w * hv.x;
                v[i * 2 + 1] += w * hv.y;
            }
        }

        // ---- halving-tree reduction: 15+2 shfls fold 16 accs -> 1 ----
#pragma unroll
        for (int st = 0; st < 4; ++st) {
            const int m  = 1 << st;
            const int nh = 8 >> st;
            const bool hi = (kg & m) != 0;
#pragma unroll
            for (int j = 0; j < 8; ++j) {
                if (j < nh) {
                    const float a0 = v[2 * j], a1 = v[2 * j + 1];
                    const float got = __shfl_xor(hi ? a0 : a1, m, 64);
                    v[j] = (hi ? a1 : a0) + got;
                }
            }
        }
        v[0] += __shfl_xor(v[0], 16, 64);
        v[0] += __shfl_xor(v[0], 32, 64);
        // lane p now holds out(p & 15), a = i*2+b

        // ---- lanes 0..15 publish their (neuron oi, batch ob) ----
        if (kg < 16) {
            const float hv = tanhf(xpv + v[0]);
            const unsigned long long u =
                ((unsigned long long)(tag0 + (unsigned)t) << 32) |
                (unsigned long long)__float_as_uint(hv);
            astore64(ex + (size_t)(t & 1) * EX_SLOT
                        + (size_t)(b0 + ob) * HID_ + ok, u);   // publish first
            *px = hv;                               // for the next-layer GEMM
        }
        // no trailing barrier: double-buffered hl (see header comment)
    }
}

__global__ __launch_bounds__(256) void copy4(
    const float4* __restrict__ src, float4* __restrict__ dst, int n4)
{
    const int i = blockIdx.x * 256 + threadIdx.x;
    if (i < n4) dst[i] = src[i];
}

extern "C" void kernel_launch(void* const* d_in, const int* in_sizes, int n_in,
                              void* d_out, int out_size, void* d_ws, size_t ws_size,
                              hipStream_t stream)
{
    const int*   tokens = (const int*)  d_in[0];
    const float* emb    = (const float*)d_in[1];
    const float* W_ih0  = (const float*)d_in[2];
    const float* W_hh0  = (const float*)d_in[3];
    const float* b_ih0  = (const float*)d_in[4];
    const float* b_hh0  = (const float*)d_in[5];
    const float* W_ih1  = (const float*)d_in[6];
    const float* W_hh1  = (const float*)d_in[7];
    const float* b_ih1  = (const float*)d_in[8];
    const float* b_hh1  = (const float*)d_in[9];
    const float* W_out  = (const float*)d_in[10];
    const float* b_out  = (const float*)d_in[11];
    float* out = (float*)d_out;

    const size_t BUF = (size_t)B_ * S_ * HID_;   // 64 MiB
    float* buf  = (float*)d_ws;
    float* buf1 = buf + BUF;                     // only if ws_size permits
    float* tmp  = (float*)d_out;                 // chunk bounce (fallback)
    unsigned long long* ex = (unsigned long long*)d_out;  // 512 KB exchange

    const int two_buf = (ws_size >= 2 * BUF * sizeof(float));  // constant/call

    // 96 KB dynamic LDS -> exactly 1 WG/CU (256 WGs co-resident on 256 CUs)
    const size_t scan_lds = 98304;
    hipFuncSetAttribute((const void*)rnn_scan_tag,
                        hipFuncAttributeMaxDynamicSharedMemorySize, (int)scan_lds);

    // 1) xp0 = gather(emb,tokens) @ W_ih0^T + b_ih0 + b_hh0  -> buf
    gemm_bias<<<dim3(HID_ / 64, M_ / 128), 256, 0, stream>>>(
        emb, tokens, W_ih0, b_ih0, b_hh0, buf, M_, EMB_, HID_);

    // 2) layer-0 scan (in place on buf; tags 1..512)
    rnn_scan_tag<<<256, 512, scan_lds, stream>>>(W_hh0, buf, ex, 1u);

    float* l1buf;
    if (two_buf) {
        // 3a) full-grid xp1 GEMM into buf1
        gemm_bias<<<dim3(HID_ / 64, M_ / 128), 256, 0, stream>>>(
            buf, nullptr, W_ih1, b_ih1, b_hh1, buf1, M_, HID_, HID_);
        l1buf = buf1;
    } else {
        // 3b) fallback: chunk through d_out (ex region dead until next scan)
        for (int c = 0; c < 16; ++c) {
            const float* Ac = buf + (size_t)c * 1024 * HID_;
            gemm_bias<<<dim3(HID_ / 64, 1024 / 128), 256, 0, stream>>>(
                Ac, nullptr, W_ih1, b_ih1, b_hh1, tmp, 1024, HID_, HID_);
            copy4<<<1024, 256, 0, stream>>>(
                (const float4*)tmp, (float4*)(buf + (size_t)c * 1024 * HID_),
                1024 * HID_ / 4);
        }
        l1buf = buf;
    }

    // 4) layer-1 scan (tags 513..1024; stale/garbage high words never match)
    rnn_scan_tag<<<256, 512, scan_lds, stream>>>(W_hh1, l1buf, ex, 513u);

    // 5) out = h1 @ W_out^T + b_out (fully rewrites d_out incl. ex region)
    gemm_bias<<<dim3(LAB_ / 64, M_ / 128), 256, 0, stream>>>(
        l1buf, nullptr, W_out, b_out, nullptr, out, M_, HID_, LAB_);
}